// Round 12
// baseline (130.973 us; speedup 1.0000x reference)
//
#include <hip/hip_runtime.h>

typedef __attribute__((ext_vector_type(8))) _Float16 half8;
typedef __attribute__((ext_vector_type(4))) float floatx4;

constexpr int NB  = 2;
constexpr int CC  = 64;
constexpr int DD  = 16;
constexpr int HH  = 32;
constexpr int WW  = 32;
constexpr int KN_ = 27;
constexpr int OC  = 64;
constexpr int DHW = DD * HH * WW;   // 16384
constexpr int TP  = 64;             // positions per block tile
constexpr int KCH = 9;              // taps per setup chunk (3 chunks of 9)

__device__ __forceinline__ unsigned short f2h(float f) {
    _Float16 h = (_Float16)f;
    return *(unsigned short*)&h;
}

// ---------------------------------------------------------------------------
// Prep kernel (merged):
//  blocks [0, 512)   : NCDHW f32 -> NDHWC f16  (64 ch contiguous per voxel)
//  blocks [512, 944) : weight (o,c,k) f32 -> f16 MFMA A-fragment stream
//    wf[(((k*2+cc)*4+ot)*64 + l)*8 + i] = W[o=ot*16+(l&15)][c=cc*32+(l>>4)*8+i][k]
__global__ __launch_bounds__(256) void k_prep(const float* __restrict__ in,
                                              const float* __restrict__ w,
                                              unsigned int* __restrict__ outu,
                                              unsigned short* __restrict__ wf) {
    int bid = blockIdx.x;
    int t = threadIdx.x;
    if (bid < 512) {
        __shared__ float tile[64][65];
        int n  = bid >> 8;
        int v0 = (bid & 255) << 6;
        int lane = t & 63, row = t >> 6;
#pragma unroll
        for (int i = 0; i < 16; ++i) {
            int c = (i << 2) + row;
            tile[c][lane] = in[(size_t)(n * CC + c) * DHW + v0 + lane];
        }
        __syncthreads();
#pragma unroll
        for (int i = 0; i < 8; ++i) {
            int flat = i * 256 + t;
            int v = flat >> 5, cd = flat & 31;
            unsigned int lo = f2h(tile[2 * cd][v]);
            unsigned int hi = f2h(tile[2 * cd + 1][v]);
            outu[(size_t)(n * DHW + v0 + v) * 32 + cd] = lo | (hi << 16);
        }
    } else {
        int f = (bid - 512) * 256 + t;   // 110592 total
        int i  = f & 7;
        int l  = (f >> 3) & 63;
        int ot = (f >> 9) & 3;
        int cc = (f >> 11) & 1;
        int k  = f >> 12;
        int o = ot * 16 + (l & 15);
        int c = cc * 32 + ((l >> 4) << 3) + i;
        wf[f] = f2h(w[(o * CC + c) * KN_ + k]);
    }
}

// ---------------------------------------------------------------------------
// TP=64 lockstep deformable conv.
// 512 blocks x 256 threads (4 waves) = 2 blocks/CU.
// Block = 64 positions, all 27 taps, all 64 outputs.
// Wave w owns o-tile w for FOUR p-subtiles -> W frags read once per (tap,cc)
// per wave, amortized over 64 positions (halves W traffic vs TP=32).
// Setup records chunked 9 taps at a time (LDS budget).
__global__ __launch_bounds__(256, 4) void k_main(const unsigned short* __restrict__ inp,
                                                 const unsigned short* __restrict__ wf,
                                                 const float* __restrict__ offs,
                                                 float* __restrict__ out) {
    __shared__ unsigned short S[2 * TP * 64];   // 16KB dbuf [buf][p64][c64] f16, chunk-XOR swz
    __shared__ uint4 SUV[KCH * TP];             // 576 recs: 8 x u16 voxel ids      (9.2KB)
    __shared__ uint4 SUW[KCH * TP];             // 576 recs: 8 x f16 corner weights (9.2KB)

    int t   = threadIdx.x;
    int bid = blockIdx.x;
    int n   = (bid >> 2) & 1;                   // XCDs 0-3 -> n=0, 4-7 -> n=1 (L2 locality)
    int idx = ((bid >> 3) << 2) | (bid & 3);    // 0..255
    int p0  = idx << 6;

    int sp = t >> 3;            // 0..31 (thread also handles sp+32)
    int cg = t & 7;             // channel chunk (16B of 128B voxel row)
    int w  = t >> 6;            // wave id == o-tile
    int l  = t & 63;
    int lrow = l & 15, lk = l >> 4;

    const float* offb = offs + (size_t)n * (3 * KN_) * DHW + p0;
    const char*  inb  = (const char*)(inp + ((size_t)n * DHW << 6));

    floatx4 acc0 = {0.f, 0.f, 0.f, 0.f};   // p-subtile 0 (p0 + lrow)
    floatx4 acc1 = {0.f, 0.f, 0.f, 0.f};   // p-subtile 1 (p0 + 16 + lrow)
    floatx4 acc2 = {0.f, 0.f, 0.f, 0.f};   // p-subtile 2 (p0 + 32 + lrow)
    floatx4 acc3 = {0.f, 0.f, 0.f, 0.f};   // p-subtile 3 (p0 + 48 + lrow)

    const int cgo   = cg << 4;
    const int woff0 = sp * 64 + ((cg ^ (sp & 7)) << 3);            // ushort units
    const int woff1 = woff0 + 32 * 64;                             // (sp+32)&7 == sp&7
    // (pt*16+lrow)&7 == lrow&7 for all pt -> same swizzle, stride 16*64
    const int roffc0 = lrow * 64 + (((0 | lk) ^ (lrow & 7)) << 3); // cc0 base (pt0)
    const int roffc1 = lrow * 64 + (((4 | lk) ^ (lrow & 7)) << 3); // cc1 base (pt0)

    for (int ch = 0; ch < 3; ++ch) {
        // ---- setup: 9x64 sampling records, coordinate math once each ----
        // (safe without pre-barrier: prior chunk's SU reads are all pre-barrier
        //  of its last tap; S untouched here)
        for (int si = t; si < KCH * TP; si += 256) {
            int kk = si >> 6, p = si & 63;
            int k  = ch * KCH + kk;
            int pa = p0 + p;
            int dpos = pa >> 10, hpos = (pa >> 5) & 31, wpos = pa & 31;

            float oz = offb[(k * 3 + 0) * DHW + p];
            float oy = offb[(k * 3 + 1) * DHW + p];
            float ox = offb[(k * 3 + 2) * DHW + p];
            float ix = ((float)wpos + ox) * (32.0f / 31.0f) - 0.5f;
            float iy = ((float)hpos + oy) * (32.0f / 31.0f) - 0.5f;
            float iz = ((float)dpos + oz) * (16.0f / 15.0f) - 0.5f;
            float xf = floorf(ix), yf = floorf(iy), zf = floorf(iz);
            float fx = ix - xf, fy = iy - yf, fz = iz - zf;
            int x0 = (int)xf, y0 = (int)yf, z0 = (int)zf;

            float wx0 = ((unsigned)x0       < (unsigned)WW) ? 1.f - fx : 0.f;
            float wx1 = ((unsigned)(x0 + 1) < (unsigned)WW) ? fx       : 0.f;
            float wy0 = ((unsigned)y0       < (unsigned)HH) ? 1.f - fy : 0.f;
            float wy1 = ((unsigned)(y0 + 1) < (unsigned)HH) ? fy       : 0.f;
            float wz0 = ((unsigned)z0       < (unsigned)DD) ? 1.f - fz : 0.f;
            float wz1 = ((unsigned)(z0 + 1) < (unsigned)DD) ? fz       : 0.f;

            int xc0 = min(max(x0, 0), WW - 1), xc1 = min(max(x0 + 1, 0), WW - 1);
            int yc0 = min(max(y0, 0), HH - 1), yc1 = min(max(y0 + 1, 0), HH - 1);
            int zc0 = min(max(z0, 0), DD - 1), zc1 = min(max(z0 + 1, 0), DD - 1);

            float wzy00 = wz0 * wy0, wzy01 = wz0 * wy1, wzy10 = wz1 * wy0, wzy11 = wz1 * wy1;
            unsigned int b00 = (zc0 * HH + yc0) * WW, b01 = (zc0 * HH + yc1) * WW;
            unsigned int b10 = (zc1 * HH + yc0) * WW, b11 = (zc1 * HH + yc1) * WW;

            uint4 vp, wp;
            vp.x = (b00 + xc0) | ((b00 + xc1) << 16);
            vp.y = (b01 + xc0) | ((b01 + xc1) << 16);
            vp.z = (b10 + xc0) | ((b10 + xc1) << 16);
            vp.w = (b11 + xc0) | ((b11 + xc1) << 16);
            wp.x = (unsigned int)f2h(wzy00 * wx0) | ((unsigned int)f2h(wzy00 * wx1) << 16);
            wp.y = (unsigned int)f2h(wzy01 * wx0) | ((unsigned int)f2h(wzy01 * wx1) << 16);
            wp.z = (unsigned int)f2h(wzy10 * wx0) | ((unsigned int)f2h(wzy10 * wx1) << 16);
            wp.w = (unsigned int)f2h(wzy11 * wx0) | ((unsigned int)f2h(wzy11 * wx1) << 16);

            SUV[si] = vp;
            SUW[si] = wp;
        }
        __syncthreads();

        // ---- lockstep per-tap loop over this chunk ----
        for (int kk = 0; kk < KCH; ++kk) {
            int k = ch * KCH + kk;

            // W fragments: wave w needs only (cc,ot=w) -> 2 x 16B per tap
            const half8 wa0 = *(const half8*)(wf + (((((k << 1) | 0) << 2) + w) << 9) + (l << 3));
            const half8 wa1 = *(const half8*)(wf + (((((k << 1) | 1) << 2) + w) << 9) + (l << 3));

            // two sampling records (positions sp and sp+32)
            const uint4 vpA = SUV[(kk << 6) + sp];
            const uint4 wpA = SUW[(kk << 6) + sp];
            const uint4 vpB = SUV[(kk << 6) + sp + 32];
            const uint4 wpB = SUW[(kk << 6) + sp + 32];
            const unsigned int vpa[4] = {vpA.x, vpA.y, vpA.z, vpA.w};
            const unsigned int wpa[4] = {wpA.x, wpA.y, wpA.z, wpA.w};
            const unsigned int vpb[4] = {vpB.x, vpB.y, vpB.z, vpB.w};
            const unsigned int wpb[4] = {wpB.x, wpB.y, wpB.z, wpB.w};

            half8 accA = {0, 0, 0, 0, 0, 0, 0, 0};
            half8 accB = {0, 0, 0, 0, 0, 0, 0, 0};
#pragma unroll
            for (int cr = 0; cr < 8; ++cr) {
                unsigned int vdA = vpa[cr >> 1];
                unsigned int vdB = vpb[cr >> 1];
                unsigned int voxA = ((cr & 1) ? (vdA >> 16) : (vdA & 0xffffu)) << 7;
                unsigned int voxB = ((cr & 1) ? (vdB >> 16) : (vdB & 0xffffu)) << 7;
                unsigned int wdA = wpa[cr >> 1];
                unsigned int wdB = wpb[cr >> 1];
                unsigned short wuA = (cr & 1) ? (unsigned short)(wdA >> 16) : (unsigned short)wdA;
                unsigned short wuB = (cr & 1) ? (unsigned short)(wdB >> 16) : (unsigned short)wdB;
                _Float16 whA = *(_Float16*)&wuA;
                _Float16 whB = *(_Float16*)&wuB;
                const half8 vA = *(const half8*)(inb + voxA + cgo);
                const half8 vB = *(const half8*)(inb + voxB + cgo);
                half8 w8A = {whA, whA, whA, whA, whA, whA, whA, whA};
                half8 w8B = {whB, whB, whB, whB, whB, whB, whB, whB};
                accA += vA * w8A;                // 4x v_pk_fma_f16 each
                accB += vB * w8B;
            }
            unsigned short* Sw = S + ((k & 1) << 12);
            *(half8*)(Sw + woff0) = accA;
            *(half8*)(Sw + woff1) = accB;

            __syncthreads();

            // MFMA: D[o16 x p16] x 4 p-subtiles, two c-chunks of 32 each
            const unsigned short* Sb = S + ((k & 1) << 12);
#pragma unroll
            for (int pt = 0; pt < 4; ++pt) {
                const half8 bf0 = *(const half8*)(Sb + roffc0 + pt * 1024);
                const half8 bf1 = *(const half8*)(Sb + roffc1 + pt * 1024);
                floatx4* ac = (pt == 0) ? &acc0 : (pt == 1) ? &acc1 : (pt == 2) ? &acc2 : &acc3;
                *ac = __builtin_amdgcn_mfma_f32_16x16x32_f16(wa0, bf0, *ac, 0, 0, 0);
                *ac = __builtin_amdgcn_mfma_f32_16x16x32_f16(wa1, bf1, *ac, 0, 0, 0);
            }
            // dbuf S: next tap's barrier orders reads vs k+2 overwrite
        }
    }

    // ---- epilogue: o = w*16 + lk*4 + r ; p = p0 + pt*16 + lrow ----
    float* ob = out + ((size_t)n * OC + (w << 4) + (lk << 2)) * DHW + p0 + lrow;
#pragma unroll
    for (int r = 0; r < 4; ++r) {
        ob[r * DHW]      = acc0[r];
        ob[r * DHW + 16] = acc1[r];
        ob[r * DHW + 32] = acc2[r];
        ob[r * DHW + 48] = acc3[r];
    }
}

// ---------------------------------------------------------------------------
// Fallback (no workspace): fp32 fused kernel, original layouts.
__global__ __launch_bounds__(256) void k_fallback(const float* __restrict__ inp,
                                                  const float* __restrict__ wt,
                                                  const float* __restrict__ offs,
                                                  float* __restrict__ out) {
    __shared__ float Slds[64][68];
    __shared__ float Wlds[64 * 64];
    int bid = blockIdx.x;
    int n = bid >> 8;
    int p0 = (bid & 255) * 64;
    int t = threadIdx.x;
    int cq = t & 15, c0 = cq << 2, pslot = t >> 4;
    int ob = (t & 15) << 2, pb = (t >> 4) << 2;
    int swz_w = (((cq & 7) ^ (cq >> 3)) << 2);
    float acc[4][4] = {};
    const float* offbase = offs + (size_t)n * (KN_ * 3) * DHW;
    for (int k = 0; k < KN_; ++k) {
#pragma unroll
        for (int i = 0; i < 16; ++i) {
            int f = i * 256 + t;
            int o = f & 63, c = f >> 6;
            Wlds[f] = wt[(o * CC + c) * KN_ + k];
        }
#pragma unroll
        for (int j = 0; j < 4; ++j) {
            int pl = pslot + 16 * j;
            int pa = p0 + pl;
            int d = pa >> 10, h = (pa >> 5) & 31, w = pa & 31;
            float offz = offbase[(k * 3 + 0) * DHW + pa];
            float offy = offbase[(k * 3 + 1) * DHW + pa];
            float offx = offbase[(k * 3 + 2) * DHW + pa];
            float ix = ((float)w + offx) * (32.0f / 31.0f) - 0.5f;
            float iy = ((float)h + offy) * (32.0f / 31.0f) - 0.5f;
            float iz = ((float)d + offz) * (16.0f / 15.0f) - 0.5f;
            float xf = floorf(ix), yf = floorf(iy), zf = floorf(iz);
            float fx = ix - xf, fy = iy - yf, fz = iz - zf;
            int x0 = (int)xf, y0 = (int)yf, z0 = (int)zf;
            float wx0 = 1.0f - fx, wx1 = fx, wy0 = 1.0f - fy, wy1 = fy, wz0 = 1.0f - fz, wz1 = fz;
            float s0 = 0.f, s1 = 0.f, s2 = 0.f, s3 = 0.f;
#pragma unroll
            for (int dz = 0; dz < 2; ++dz) {
                int zc = z0 + dz;
                if ((unsigned)zc >= (unsigned)DD) continue;
                float wz = dz ? wz1 : wz0;
#pragma unroll
                for (int dy = 0; dy < 2; ++dy) {
                    int yc = y0 + dy;
                    if ((unsigned)yc >= (unsigned)HH) continue;
                    float wzy = wz * (dy ? wy1 : wy0);
#pragma unroll
                    for (int dx = 0; dx < 2; ++dx) {
                        int xc = x0 + dx;
                        if ((unsigned)xc >= (unsigned)WW) continue;
                        float wf = wzy * (dx ? wx1 : wx0);
                        int vox = (zc * HH + yc) * WW + xc;
                        const float* b = inp + (size_t)(n * CC + c0) * DHW + vox;
                        s0 += wf * b[0]; s1 += wf * b[DHW];
                        s2 += wf * b[2 * DHW]; s3 += wf * b[3 * DHW];
                    }
                }
            }
            int plw = pl ^ swz_w;
            Slds[c0 + 0][plw] = s0; Slds[c0 + 1][plw] = s1;
            Slds[c0 + 2][plw] = s2; Slds[c0 + 3][plw] = s3;
        }
        __syncthreads();
#pragma unroll
        for (int c = 0; c < 64; ++c) {
            const int g = ((c >> 2) & 7) ^ (c >> 5);
            float4 wv = *(const float4*)(Wlds + c * 64 + ob);
            float4 sv = *(const float4*)(&Slds[c][pb ^ (g << 2)]);
            float wa[4] = {wv.x, wv.y, wv.z, wv.w};
            float sa[4] = {sv.x, sv.y, sv.z, sv.w};
#pragma unroll
            for (int i = 0; i < 4; ++i)
#pragma unroll
                for (int jj = 0; jj < 4; ++jj) acc[i][jj] += wa[i] * sa[jj];
        }
        __syncthreads();
    }
#pragma unroll
    for (int i = 0; i < 4; ++i) {
        float4 vv;
        vv.x = acc[i][0]; vv.y = acc[i][1]; vv.z = acc[i][2]; vv.w = acc[i][3];
        *(float4*)(out + (size_t)(n * OC + ob + i) * DHW + p0 + pb) = vv;
    }
}

// ---------------------------------------------------------------------------
extern "C" void kernel_launch(void* const* d_in, const int* in_sizes, int n_in,
                              void* d_out, int out_size, void* d_ws, size_t ws_size,
                              hipStream_t stream) {
    const float* inp = (const float*)d_in[0];
    const float* off = (const float*)d_in[1];
    const float* wgt = (const float*)d_in[2];
    float* out = (float*)d_out;

    const size_t in_f16_bytes = (size_t)NB * DHW * CC * 2;           // 4 MB
    const size_t wf_bytes     = (size_t)KN_ * 2 * 4 * 64 * 8 * 2;    // 216 KB

    if (ws_size >= in_f16_bytes + wf_bytes) {
        unsigned int*   in_t = (unsigned int*)d_ws;
        unsigned short* w_f  = (unsigned short*)((char*)d_ws + in_f16_bytes);
        k_prep<<<dim3(512 + 432), dim3(256), 0, stream>>>(inp, wgt, in_t, w_f);
        k_main<<<dim3(512), dim3(256), 0, stream>>>(
            (const unsigned short*)in_t, w_f, off, out);
    } else {
        k_fallback<<<dim3(NB * 256), dim3(256), 0, stream>>>(inp, wgt, off, out);
    }
}